// Round 6
// baseline (489.453 us; speedup 1.0000x reference)
//
#include <hip/hip_runtime.h>
#include <stdint.h>

#define S_LEN 1024
#define HDIM  4096
#define NHEAD 32
#define DHEAD 128
#define BATCH 2
#define MTOK  (BATCH * S_LEN)   // 2048

typedef __attribute__((ext_vector_type(4))) int   i32x4;
typedef __attribute__((ext_vector_type(4))) float f32x4;
typedef __attribute__((ext_vector_type(8))) short bf16x8;

#define GLOBAL_AS __attribute__((address_space(1)))
#define LDS_AS    __attribute__((address_space(3)))

__device__ __forceinline__ void gl2lds16(const void* g, void* l) {
  __builtin_amdgcn_global_load_lds((const GLOBAL_AS unsigned int*)(g),
                                   (LDS_AS unsigned int*)(l), 16, 0, 0);
}

// float -> bf16 bits, round-to-nearest-even (exact for small ints)
__device__ __forceinline__ unsigned short f2bf(float f) {
  unsigned int u = __float_as_uint(f);
  unsigned int r = (u + 0x7fffu + ((u >> 16) & 1u)) >> 16;
  return (unsigned short)r;
}

// -------- per-row symmetric fake-quant: x (row of 4096 f32) -> int8 + scale --------
__global__ __launch_bounds__(256) void rowquant_kernel(
    const float* __restrict__ x, int8_t* __restrict__ q,
    float* __restrict__ scales, float qmax, float clipLo)
{
  const int row = blockIdx.x;
  const int t = threadIdx.x;
  const float* xr = x + (size_t)row * HDIM;
  float4 v[4];
  float am = 0.f;
#pragma unroll
  for (int i = 0; i < 4; ++i) {
    v[i] = ((const float4*)xr)[t + 256 * i];
    am = fmaxf(am, fmaxf(fmaxf(fabsf(v[i].x), fabsf(v[i].y)),
                         fmaxf(fabsf(v[i].z), fabsf(v[i].w))));
  }
#pragma unroll
  for (int off = 32; off > 0; off >>= 1) am = fmaxf(am, __shfl_down(am, off));
  __shared__ float wred[4];
  if ((t & 63) == 0) wred[t >> 6] = am;
  __syncthreads();
  const float m = fmaxf(fmaxf(wred[0], wred[1]), fmaxf(wred[2], wred[3]));
  const float scale = fmaxf(m / qmax, 1e-8f);
  if (t == 0) scales[row] = scale;
  int* qo = (int*)(q + (size_t)row * HDIM);
#pragma unroll
  for (int i = 0; i < 4; ++i) {
    int b0 = (int)fminf(fmaxf(rintf(v[i].x / scale), clipLo), qmax);
    int b1 = (int)fminf(fmaxf(rintf(v[i].y / scale), clipLo), qmax);
    int b2 = (int)fminf(fmaxf(rintf(v[i].z / scale), clipLo), qmax);
    int b3 = (int)fminf(fmaxf(rintf(v[i].w / scale), clipLo), qmax);
    qo[t + 256 * i] = (b0 & 0xff) | ((b1 & 0xff) << 8) | ((b2 & 0xff) << 16) | ((b3 & 0xff) << 24);
  }
}

// ======== i8 MFMA GEMM, 8-phase counted-vmcnt template (T3+T4+T5) ========
// BM=128, BN=256, BK=128 bytes. 8 waves, wave tile 64x64. 256 blocks.
// LDS: dbuf x (A 128x128B + B 256x128B) = 96 KB.
struct FragQ { i32x4 a[2][2]; i32x4 b[2][2]; };

template<int MH, int NH>
__device__ __forceinline__ FragQ qread(const int8_t* aB, const int8_t* bB,
                                       int wm, int wn, int l15, int lg) {
  FragQ f;
#pragma unroll
  for (int q = 0; q < 2; ++q)
#pragma unroll
    for (int kk = 0; kk < 2; ++kk) {
      const int Ra = wm * 64 + MH * 32 + q * 16 + l15;
      f.a[q][kk] = *(const i32x4*)(aB + Ra * 128 + ((((kk << 2) + lg) ^ (Ra & 7)) << 4));
      const int Rb = wn * 64 + NH * 32 + q * 16 + l15;
      f.b[q][kk] = *(const i32x4*)(bB + Rb * 128 + ((((kk << 2) + lg) ^ (Rb & 7)) << 4));
    }
  return f;
}

template<int MH, int NH>
__device__ __forceinline__ void qmfma(const FragQ& f, i32x4 (&acc)[4][4]) {
#pragma unroll
  for (int q = 0; q < 2; ++q)
#pragma unroll
    for (int n2 = 0; n2 < 2; ++n2)
#pragma unroll
      for (int kk = 0; kk < 2; ++kk)
        acc[MH * 2 + q][NH * 2 + n2] = __builtin_amdgcn_mfma_i32_16x16x64_i8(
            f.a[q][kk], f.b[n2][kk], acc[MH * 2 + q][NH * 2 + n2], 0, 0, 0);
}

#define GPHASE(MH, NH, CB, STAGE_STMT, WAIT_STMT)                    \
  {                                                                  \
    FragQ f = qread<MH, NH>(aLds[CB], bLds[CB], wm, wn, l15, lg);    \
    STAGE_STMT;                                                      \
    __builtin_amdgcn_s_barrier();                                    \
    asm volatile("s_waitcnt lgkmcnt(0)" ::: "memory");               \
    __builtin_amdgcn_sched_barrier(0);                               \
    __builtin_amdgcn_s_setprio(1);                                   \
    qmfma<MH, NH>(f, acc);                                           \
    __builtin_amdgcn_s_setprio(0);                                   \
    WAIT_STMT;                                                       \
    __builtin_amdgcn_s_barrier();                                    \
  }

__global__ __launch_bounds__(512, 1) void gemm_i8_mfma8p_kernel(
    const int8_t* __restrict__ A, const float* __restrict__ sa,
    const int8_t* __restrict__ Bw, const float* __restrict__ sb,
    float* __restrict__ C)
{
  __shared__ __align__(16) int8_t aLds[2][128 * 128];   // 32 KB
  __shared__ __align__(16) int8_t bLds[2][256 * 128];   // 64 KB

  // XCD-chunked bijective swizzle over 256 blocks: 32/XCD, 2 B-panels per XCD
  const int flat = blockIdx.x;
  const int nf = (flat & 7) * 32 + (flat >> 3);
  const int bni = nf >> 4, bmi = nf & 15;
  const int bm = bmi * 128, bn = bni * 256;

  const int tid = threadIdx.x;
  const int w = tid >> 6, l = tid & 63;
  const int l15 = l & 15, lg = l >> 4;
  const int lr = l >> 3, g7 = l & 7;
  const int wm = w >> 2, wn = w & 3;

  // per-lane staging source base (pre-swizzled granule: LDS[r][g] = A[r][g^(r&7)])
  const int8_t* aT = A + (size_t)(bm + lr) * HDIM + ((g7 ^ lr) << 4);
  const int8_t* bT = Bw + (size_t)(bn + lr) * HDIM + ((g7 ^ lr) << 4);

  // stage A-half h (rows {wm'*64 + h*32 .. +31}) of K-tile `tile`: 1 gl2lds/wave
  auto stageA = [&](int h, int tile) {
    const int r0 = (w >> 2) * 64 + h * 32 + (w & 3) * 8;
    gl2lds16(aT + (size_t)r0 * HDIM + tile * 128, aLds[tile & 1] + r0 * 128);
  };
  // stage B-half h (rows {wn'*64 + h*32 .. +31}, 4 strips): 2 gl2lds/wave
  auto stageB = [&](int h, int tile) {
#pragma unroll
    for (int ii = 0; ii < 2; ++ii) {
      const int r0 = (w & 3) * 64 + h * 32 + (w >> 2) * 16 + ii * 8;
      gl2lds16(bT + (size_t)r0 * HDIM + tile * 128, bLds[tile & 1] + r0 * 128);
    }
  };

  i32x4 acc[4][4];
#pragma unroll
  for (int i = 0; i < 4; ++i)
#pragma unroll
    for (int j = 0; j < 4; ++j) acc[i][j] = (i32x4){0, 0, 0, 0};

  // ---- prologue: tile0 fully + A0,B0 of tile1 (9 loads/wave) ----
  stageA(0, 0); stageB(0, 0); stageA(1, 0); stageB(1, 0);
  stageA(0, 1); stageB(0, 1);
  asm volatile("s_waitcnt vmcnt(3)" ::: "memory");   // tile0 landed
  __builtin_amdgcn_s_barrier();

  // ---- main loop: 16 iters x 2 K-tiles x 4 quadrant-phases ----
  for (int it = 0; it < 16; ++it) {
    const int tA = it * 2;          // even tile -> buf0; tA+1 -> buf1
    const bool last = (it == 15);
    GPHASE(0, 0, 0, stageA(1, tA + 1), );
    GPHASE(0, 1, 0, stageB(1, tA + 1), );
    GPHASE(1, 0, 0, if (!last) stageA(0, tA + 2), );
    GPHASE(1, 1, 0, if (!last) stageB(0, tA + 2),
           if (last) { asm volatile("s_waitcnt vmcnt(0)" ::: "memory"); }
           else      { asm volatile("s_waitcnt vmcnt(3)" ::: "memory"); });
    GPHASE(0, 0, 1, if (!last) stageA(1, tA + 2), );
    GPHASE(0, 1, 1, if (!last) stageB(1, tA + 2), );
    GPHASE(1, 0, 1, if (!last) stageA(0, tA + 3), );
    GPHASE(1, 1, 1, if (!last) stageB(0, tA + 3),
           if (!last) { asm volatile("s_waitcnt vmcnt(3)" ::: "memory"); });
  }

  // ---- epilogue ----
  float sbr[4];
#pragma unroll
  for (int j = 0; j < 4; ++j) sbr[j] = sb[bn + wn * 64 + j * 16 + l15];
#pragma unroll
  for (int i = 0; i < 4; ++i) {
#pragma unroll
    for (int r = 0; r < 4; ++r) {
      const int m = bm + wm * 64 + i * 16 + lg * 4 + r;
      const float sm = sa[m];
      float* cp = C + (size_t)m * HDIM + bn + wn * 64 + l15;
#pragma unroll
      for (int j = 0; j < 4; ++j)
        cp[j * 16] = sm * sbr[j] * (float)acc[i][j][r];
    }
  }
}

// -------- RoPE + per-(b,s,h) fake-quant8 for Q,K; layout [bh][s][128] --------
__global__ __launch_bounds__(256) void rope_quant_kernel(
    const float* __restrict__ y, int8_t* __restrict__ o8,
    float* __restrict__ oscale, int doRope)
{
  const int gw = (blockIdx.x * 256 + threadIdx.x) >> 6;
  const int lane = threadIdx.x & 63;
  const int h = gw & (NHEAD - 1);
  const int tok = gw >> 5;
  const int s = tok & (S_LEN - 1);
  const float* yr = y + (size_t)tok * HDIM + h * DHEAD;
  float x0 = yr[lane], x1 = yr[lane + 64];
  float o0, o1;
  if (doRope) {
    const float e = (float)lane * (1.0f / 64.0f);
    const float inv = powf(10000.0f, -e);
    const float ang = (float)s * inv;
    float sn, c;
    sincosf(ang, &sn, &c);
    o0 = x0 * c - x1 * sn;
    o1 = x1 * c + x0 * sn;
  } else {
    o0 = x0; o1 = x1;
  }
  float am = fmaxf(fabsf(o0), fabsf(o1));
#pragma unroll
  for (int off = 32; off > 0; off >>= 1) am = fmaxf(am, __shfl_xor(am, off));
  const float scale = fmaxf(am / 127.0f, 1e-8f);
  const float q0 = fminf(fmaxf(rintf(o0 / scale), -128.f), 127.f);
  const float q1 = fminf(fmaxf(rintf(o1 / scale), -128.f), 127.f);
  const size_t orow = (size_t)((tok >> 10) * NHEAD + h) * S_LEN + s;
  int8_t* op = o8 + orow * DHEAD;
  op[lane] = (int8_t)(int)q0;
  op[lane + 64] = (int8_t)(int)q1;
  if (lane == 0) oscale[orow] = scale;
}

// -------- V: quant per (b,h,s) row, fold sv in, store TRANSPOSED bf16 [bh][d][s] --------
__global__ __launch_bounds__(256) void vtrans_kernel(
    const float* __restrict__ y, unsigned short* __restrict__ vqT)
{
  __shared__ unsigned short vt[128][80];
  const int tid = threadIdx.x;
  const int wv = tid >> 6, lane = tid & 63;
  const int bh = blockIdx.y, s0 = blockIdx.x * 64;
  const int b = bh >> 5, h = bh & 31;
  for (int it = 0; it < 16; ++it) {
    const int tl = wv * 16 + it;
    const float* yr = y + ((size_t)(b * S_LEN + s0 + tl)) * HDIM + h * DHEAD;
    float x0 = yr[lane], x1 = yr[lane + 64];
    float am = fmaxf(fabsf(x0), fabsf(x1));
#pragma unroll
    for (int off = 32; off > 0; off >>= 1) am = fmaxf(am, __shfl_xor(am, off));
    const float scale = fmaxf(am / 127.0f, 1e-8f);
    const float q0 = fminf(fmaxf(rintf(x0 / scale), -128.f), 127.f);
    const float q1 = fminf(fmaxf(rintf(x1 / scale), -128.f), 127.f);
    vt[lane][tl] = f2bf(q0 * scale);
    vt[lane + 64][tl] = f2bf(q1 * scale);
  }
  __syncthreads();
  const int d = tid >> 1, half = tid & 1;
  unsigned short* op = vqT + ((size_t)bh * 128 + d) * S_LEN + s0 + half * 32;
#pragma unroll
  for (int c = 0; c < 4; ++c)
    *(i32x4*)(op + c * 8) = *(const i32x4*)(&vt[d][half * 32 + c * 8]);
}

// -------- MFMA flash attention, causal-balanced: block does q-tiles (bx, 15-bx) --------
#define QB 64
#define KB 64

__global__ __launch_bounds__(256) void attn_mfma_kernel(
    const int8_t* __restrict__ qq, const float* __restrict__ sq,
    const int8_t* __restrict__ kq, const float* __restrict__ sk,
    const unsigned short* __restrict__ vqT,   // bf16 bits, sv pre-folded
    float* __restrict__ attn)
{
  __shared__ __align__(16) int8_t ks[KB * 128];
  __shared__ __align__(16) unsigned short vs[128 * 64];
  __shared__ __align__(16) unsigned short ps[QB][64];
  __shared__ float sk_t[KB];

  const int tid = threadIdx.x;
  const int w = tid >> 6;
  const int l = tid & 63;
  const int l15 = l & 15;
  const int lg = l >> 4;
  const int lr = l >> 3, g7 = l & 7;
  const int bh = blockIdx.y;
  const size_t bhS = (size_t)bh * S_LEN;
  const int b = bh >> 5, h = bh & 31;
  const int NT = S_LEN / QB;   // 16

  for (int rep = 0; rep < 2; ++rep) {
    const int qt = rep ? (NT - 1 - (int)blockIdx.x) : (int)blockIdx.x;
    const int q0 = qt * QB;
    const int nkt = qt + 1;

    const int qrow = q0 + w * 16 + l15;
    const int8_t* qp = qq + (bhS + qrow) * (size_t)DHEAD;
    const i32x4 qa0 = *(const i32x4*)(qp + lg * 16);
    const i32x4 qa1 = *(const i32x4*)(qp + 64 + lg * 16);

    float sqv[4];
    int qg[4];
#pragma unroll
    for (int r = 0; r < 4; ++r) {
      qg[r] = q0 + w * 16 + lg * 4 + r;
      sqv[r] = sq[bhS + qg[r]] * 0.08838834764831843f * 1.4426950408889634f;
    }

    float rmax[4] = {-3.0e38f, -3.0e38f, -3.0e38f, -3.0e38f};

    // ---------- pass 1: exact row max (log2 domain) ----------
    for (int kt = 0; kt < nkt; ++kt) {
      const int k0 = kt * KB;
#pragma unroll
      for (int i = 0; i < 2; ++i) {
        const int r0 = w * 16 + i * 8;
        gl2lds16(kq + (bhS + k0 + r0 + lr) * (size_t)128 + ((g7 ^ lr) << 4),
                 ks + r0 * 128);
      }
      if (tid < KB) sk_t[tid] = sk[bhS + k0 + tid];
      __syncthreads();
      const bool diag = (kt == nkt - 1);
#pragma unroll
      for (int c = 0; c < 4; ++c) {
        const int krow = c * 16 + l15;
        const i32x4 b0 = *(const i32x4*)(ks + krow * 128 + ((lg ^ (krow & 7)) << 4));
        const i32x4 b1 = *(const i32x4*)(ks + krow * 128 + (((lg + 4) ^ (krow & 7)) << 4));
        i32x4 acc = {0, 0, 0, 0};
        acc = __builtin_amdgcn_mfma_i32_16x16x64_i8(qa0, b0, acc, 0, 0, 0);
        acc = __builtin_amdgcn_mfma_i32_16x16x64_i8(qa1, b1, acc, 0, 0, 0);
        const float skv = sk_t[krow];
        const int kgl = k0 + krow;
#pragma unroll
        for (int r = 0; r < 4; ++r) {
          const float s = (float)acc[r] * sqv[r] * skv;
          if (!diag || (kgl <= qg[r])) rmax[r] = fmaxf(rmax[r], s);
        }
      }
      __syncthreads();
    }
#pragma unroll
    for (int r = 0; r < 4; ++r)
#pragma unroll
      for (int off = 1; off < 16; off <<= 1)
        rmax[r] = fmaxf(rmax[r], __shfl_xor(rmax[r], off));

    // ---------- pass 2: P quant + PV ----------
    float rs[4] = {0.f, 0.f, 0.f, 0.f};
    f32x4 oacc[8];
#pragma unroll
    for (int ds = 0; ds < 8; ++ds) oacc[ds] = (f32x4){0.f, 0.f, 0.f, 0.f};

    const int qloc = w * 16 + l15;
    const int swA0 = (lg ^ (qloc & 7)) << 3;
    const int swA1 = ((lg + 4) ^ (qloc & 7)) << 3;

    for (int kt = 0; kt < nkt; ++kt) {
      const int k0 = kt * KB;
#pragma unroll
      for (int i = 0; i < 2; ++i) {
        const int r0 = w * 16 + i * 8;
        gl2lds16(kq + (bhS + k0 + r0 + lr) * (size_t)128 + ((g7 ^ lr) << 4),
                 ks + r0 * 128);
      }
#pragma unroll
      for (int i = 0; i < 4; ++i) {
        const int r0 = w * 32 + i * 8;
        const unsigned short* src = vqT + ((size_t)bh * 128 + r0 + lr) * S_LEN
                                        + k0 + ((g7 ^ lr) << 3);
        gl2lds16(src, vs + r0 * 64);
      }
      if (tid < KB) sk_t[tid] = sk[bhS + k0 + tid];
      __syncthreads();
      const bool diag = (kt == nkt - 1);

#pragma unroll
      for (int c = 0; c < 4; ++c) {
        const int krow = c * 16 + l15;
        const i32x4 b0 = *(const i32x4*)(ks + krow * 128 + ((lg ^ (krow & 7)) << 4));
        const i32x4 b1 = *(const i32x4*)(ks + krow * 128 + (((lg + 4) ^ (krow & 7)) << 4));
        i32x4 acc = {0, 0, 0, 0};
        acc = __builtin_amdgcn_mfma_i32_16x16x64_i8(qa0, b0, acc, 0, 0, 0);
        acc = __builtin_amdgcn_mfma_i32_16x16x64_i8(qa1, b1, acc, 0, 0, 0);
        const float skv = sk_t[krow];
        const int kgl = k0 + krow;
#pragma unroll
        for (int r = 0; r < 4; ++r) {
          const float s2 = (float)acc[r] * sqv[r] * skv;
          const bool valid = !diag || (kgl <= qg[r]);
          const float e = valid ? exp2f(s2 - rmax[r]) : 0.0f;
          rs[r] += e;
          const float p = rintf(e * 127.0f);
          const int qr = w * 16 + lg * 4 + r;
          const int sidx = (((krow >> 3) ^ (qr & 7)) << 3) | (krow & 7);
          ps[qr][sidx] = f2bf(p);
        }
      }

      const bf16x8 a0 = *(const bf16x8*)&ps[qloc][swA0];
      const bf16x8 a1 = *(const bf16x8*)&ps[qloc][swA1];
#pragma unroll
      for (int ds = 0; ds < 8; ++ds) {
        const int d = ds * 16 + l15;
        const bf16x8 bv0 = *(const bf16x8*)(vs + d * 64 + ((lg ^ (d & 7)) << 3));
        const bf16x8 bv1 = *(const bf16x8*)(vs + d * 64 + (((lg + 4) ^ (d & 7)) << 3));
        oacc[ds] = __builtin_amdgcn_mfma_f32_16x16x32_bf16(a0, bv0, oacc[ds], 0, 0, 0);
        oacc[ds] = __builtin_amdgcn_mfma_f32_16x16x32_bf16(a1, bv1, oacc[ds], 0, 0, 0);
      }
      __syncthreads();
    }

    // ---------- epilogue ----------
#pragma unroll
    for (int r = 0; r < 4; ++r)
#pragma unroll
      for (int off = 1; off < 16; off <<= 1)
        rs[r] += __shfl_xor(rs[r], off);

#pragma unroll
    for (int r = 0; r < 4; ++r) {
      const float inv = 1.0f / (127.0f * rs[r]);
      float* op = attn + ((size_t)(b * S_LEN + qg[r])) * HDIM + h * DHEAD + l15;
#pragma unroll
      for (int ds = 0; ds < 8; ++ds)
        op[ds * 16] = oacc[ds][r] * inv;
    }
  }
}

extern "C" void kernel_launch(void* const* d_in, const int* in_sizes, int n_in,
                              void* d_out, int out_size, void* d_ws, size_t ws_size,
                              hipStream_t stream) {
  const float* hs = (const float*)d_in[0];
  const float* wmat[4] = { (const float*)d_in[1], (const float*)d_in[2],
                           (const float*)d_in[3], (const float*)d_in[4] };

  char* p = (char*)d_ws;
  auto take = [&](size_t sz) { char* r = p; p += (sz + 255) & ~(size_t)255; return r; };

  int8_t* xq8 = (int8_t*)take((size_t)MTOK * HDIM);
  int8_t* w4[4];
  for (int i = 0; i < 4; ++i) w4[i] = (int8_t*)take((size_t)HDIM * HDIM);
  float* sx = (float*)take((size_t)MTOK * 4);
  float* sw[4];
  for (int i = 0; i < 4; ++i) sw[i] = (float*)take((size_t)HDIM * 4);
  float* y = (float*)take((size_t)MTOK * HDIM * 4);
  int8_t* qq8 = (int8_t*)take((size_t)MTOK * HDIM);
  int8_t* kq8 = (int8_t*)take((size_t)MTOK * HDIM);
  unsigned short* vqT = (unsigned short*)take((size_t)MTOK * HDIM * 2);
  float* sqs = (float*)take((size_t)BATCH * NHEAD * S_LEN * 4);
  float* sks = (float*)take((size_t)BATCH * NHEAD * S_LEN * 4);
  float* sattn = (float*)take((size_t)MTOK * 4);

  rowquant_kernel<<<MTOK, 256, 0, stream>>>(hs, xq8, sx, 127.f, -128.f);
  for (int i = 0; i < 4; ++i)
    rowquant_kernel<<<HDIM, 256, 0, stream>>>(wmat[i], w4[i], sw[i], 7.f, -8.f);

  const int gblocks = (MTOK / 128) * (HDIM / 256);  // 256
  gemm_i8_mfma8p_kernel<<<gblocks, 512, 0, stream>>>(xq8, sx, w4[0], sw[0], y);
  rope_quant_kernel<<<MTOK * NHEAD / 4, 256, 0, stream>>>(y, qq8, sqs, 1);
  gemm_i8_mfma8p_kernel<<<gblocks, 512, 0, stream>>>(xq8, sx, w4[1], sw[1], y);
  rope_quant_kernel<<<MTOK * NHEAD / 4, 256, 0, stream>>>(y, kq8, sks, 1);
  gemm_i8_mfma8p_kernel<<<gblocks, 512, 0, stream>>>(xq8, sx, w4[2], sw[2], y);
  vtrans_kernel<<<dim3(S_LEN / 64, BATCH * NHEAD), 256, 0, stream>>>(y, vqT);

  attn_mfma_kernel<<<dim3(S_LEN / QB / 2, BATCH * NHEAD), 256, 0, stream>>>(
      qq8, sqs, kq8, sks, vqT, y);

  rowquant_kernel<<<MTOK, 256, 0, stream>>>(y, xq8, sattn, 127.f, -128.f);
  gemm_i8_mfma8p_kernel<<<gblocks, 512, 0, stream>>>(xq8, sattn, w4[3], sw[3], (float*)d_out);
}

// Round 7
// 404.921 us; speedup vs baseline: 1.2088x; 1.2088x over previous
//
#include <hip/hip_runtime.h>
#include <stdint.h>

#define S_LEN 1024
#define HDIM  4096
#define NHEAD 32
#define DHEAD 128
#define BATCH 2
#define MTOK  (BATCH * S_LEN)   // 2048

typedef __attribute__((ext_vector_type(4))) int   i32x4;
typedef __attribute__((ext_vector_type(4))) float f32x4;
typedef __attribute__((ext_vector_type(8))) short bf16x8;

#define GLOBAL_AS __attribute__((address_space(1)))
#define LDS_AS    __attribute__((address_space(3)))

__device__ __forceinline__ void gl2lds16(const void* g, void* l) {
  __builtin_amdgcn_global_load_lds((const GLOBAL_AS unsigned int*)(g),
                                   (LDS_AS unsigned int*)(l), 16, 0, 0);
}

// float -> bf16 bits, round-to-nearest-even (exact for small ints)
__device__ __forceinline__ unsigned short f2bf(float f) {
  unsigned int u = __float_as_uint(f);
  unsigned int r = (u + 0x7fffu + ((u >> 16) & 1u)) >> 16;
  return (unsigned short)r;
}

// -------- per-row symmetric fake-quant: x (row of 4096 f32) -> int8 + scale --------
__global__ __launch_bounds__(256) void rowquant_kernel(
    const float* __restrict__ x, int8_t* __restrict__ q,
    float* __restrict__ scales, float qmax, float clipLo)
{
  const int row = blockIdx.x;
  const int t = threadIdx.x;
  const float* xr = x + (size_t)row * HDIM;
  float4 v[4];
  float am = 0.f;
#pragma unroll
  for (int i = 0; i < 4; ++i) {
    v[i] = ((const float4*)xr)[t + 256 * i];
    am = fmaxf(am, fmaxf(fmaxf(fabsf(v[i].x), fabsf(v[i].y)),
                         fmaxf(fabsf(v[i].z), fabsf(v[i].w))));
  }
#pragma unroll
  for (int off = 32; off > 0; off >>= 1) am = fmaxf(am, __shfl_down(am, off));
  __shared__ float wred[4];
  if ((t & 63) == 0) wred[t >> 6] = am;
  __syncthreads();
  const float m = fmaxf(fmaxf(wred[0], wred[1]), fmaxf(wred[2], wred[3]));
  const float scale = fmaxf(m / qmax, 1e-8f);
  if (t == 0) scales[row] = scale;
  int* qo = (int*)(q + (size_t)row * HDIM);
#pragma unroll
  for (int i = 0; i < 4; ++i) {
    int b0 = (int)fminf(fmaxf(rintf(v[i].x / scale), clipLo), qmax);
    int b1 = (int)fminf(fmaxf(rintf(v[i].y / scale), clipLo), qmax);
    int b2 = (int)fminf(fmaxf(rintf(v[i].z / scale), clipLo), qmax);
    int b3 = (int)fminf(fmaxf(rintf(v[i].w / scale), clipLo), qmax);
    qo[t + 256 * i] = (b0 & 0xff) | ((b1 & 0xff) << 8) | ((b2 & 0xff) << 16) | ((b3 & 0xff) << 24);
  }
}

// ======== i8 MFMA GEMM: 128x128 tile, BK=128B, 4 waves, TRUE 2-phase dbuf ========
// Per K-step: stage(t+1 -> other buf) | compute(buf) | vmcnt(0) [~free] | s_barrier.
// 64 KB LDS -> 2 blocks/CU; co-resident blocks + self-hiding drain.
__global__ __launch_bounds__(256, 2) void gemm_i8_dbuf_kernel(
    const int8_t* __restrict__ A, const float* __restrict__ sa,
    const int8_t* __restrict__ Bw, const float* __restrict__ sb,
    float* __restrict__ C)
{
  __shared__ __align__(16) int8_t asB[2][128 * 128];
  __shared__ __align__(16) int8_t bsB[2][128 * 128];

  // XCD-chunked bijective swizzle over 512 blocks (64/XCD); bmi fastest ->
  // consecutive co-resident blocks share the B-panel (L2 reuse).
  const int flat = blockIdx.y * gridDim.x + blockIdx.x;
  const int nf = (flat & 7) * 64 + (flat >> 3);
  const int bmi = nf & 15, bni = nf >> 4;
  const int bm = bmi * 128, bn = bni * 128;

  const int tid = threadIdx.x;
  const int w = tid >> 6, l = tid & 63;
  const int l15 = l & 15, lg = l >> 4, l7 = l & 7;
  const int lr = l >> 3, g7 = l & 7;
  const int m0 = (w >> 1) * 64, n0 = (w & 1) * 64;

  // pre-swizzled global source (slot = g ^ (row&7)); LDS dest linear
  const int8_t* aT = A + (size_t)(bm + lr) * HDIM + ((g7 ^ lr) << 4);
  const int8_t* bT = Bw + (size_t)(bn + lr) * HDIM + ((g7 ^ lr) << 4);

  i32x4 acc[4][4];
#pragma unroll
  for (int i = 0; i < 4; ++i)
#pragma unroll
    for (int j = 0; j < 4; ++j) acc[i][j] = (i32x4){0, 0, 0, 0};

  auto stage = [&](int t) {
    const int bf = t & 1;
    const size_t k = (size_t)t * 128;
#pragma unroll
    for (int i = 0; i < 4; ++i) {
      const int r0 = w * 32 + i * 8;             // wave-uniform row base
      gl2lds16(aT + (size_t)r0 * HDIM + k, asB[bf] + r0 * 128);
      gl2lds16(bT + (size_t)r0 * HDIM + k, bsB[bf] + r0 * 128);
    }
  };

  // prologue
  stage(0);
  asm volatile("s_waitcnt vmcnt(0)" ::: "memory");
  __builtin_amdgcn_s_barrier();

  for (int t = 0; t < 32; ++t) {
    if (t < 31) stage(t + 1);                    // issue-early into other buf
    const int cur = t & 1;
    __builtin_amdgcn_s_setprio(1);
#pragma unroll
    for (int kk = 0; kk < 2; ++kk) {
      i32x4 aF[4], bF[4];
      const int slot = (((kk << 2) + lg) ^ l7) << 4;
#pragma unroll
      for (int i = 0; i < 4; ++i)
        aF[i] = *(const i32x4*)(asB[cur] + (m0 + i * 16 + l15) * 128 + slot);
#pragma unroll
      for (int j = 0; j < 4; ++j)
        bF[j] = *(const i32x4*)(bsB[cur] + (n0 + j * 16 + l15) * 128 + slot);
#pragma unroll
      for (int i = 0; i < 4; ++i)
#pragma unroll
        for (int j = 0; j < 4; ++j)
          acc[i][j] = __builtin_amdgcn_mfma_i32_16x16x64_i8(aF[i], bF[j], acc[i][j], 0, 0, 0);
    }
    __builtin_amdgcn_s_setprio(0);
    if (t < 31) {
      asm volatile("s_waitcnt vmcnt(0)" ::: "memory");  // next tile landed (latency already hidden)
      __builtin_amdgcn_s_barrier();                      // buf reuse safety
    }
  }

  // epilogue: C row = bm+m0+i*16+lg*4+r, col = bn+n0+j*16+l15
  float sbr[4];
#pragma unroll
  for (int j = 0; j < 4; ++j) sbr[j] = sb[bn + n0 + j * 16 + l15];
#pragma unroll
  for (int i = 0; i < 4; ++i) {
#pragma unroll
    for (int r = 0; r < 4; ++r) {
      const int m = bm + m0 + i * 16 + lg * 4 + r;
      const float sm = sa[m];
      float* cp = C + (size_t)m * HDIM + bn + n0 + l15;
#pragma unroll
      for (int j = 0; j < 4; ++j)
        cp[j * 16] = sm * sbr[j] * (float)acc[i][j][r];
    }
  }
}

// -------- RoPE + per-(b,s,h) fake-quant8 for Q,K; layout [bh][s][128] --------
__global__ __launch_bounds__(256) void rope_quant_kernel(
    const float* __restrict__ y, int8_t* __restrict__ o8,
    float* __restrict__ oscale, int doRope)
{
  const int gw = (blockIdx.x * 256 + threadIdx.x) >> 6;
  const int lane = threadIdx.x & 63;
  const int h = gw & (NHEAD - 1);
  const int tok = gw >> 5;
  const int s = tok & (S_LEN - 1);
  const float* yr = y + (size_t)tok * HDIM + h * DHEAD;
  float x0 = yr[lane], x1 = yr[lane + 64];
  float o0, o1;
  if (doRope) {
    const float e = (float)lane * (1.0f / 64.0f);
    const float inv = powf(10000.0f, -e);
    const float ang = (float)s * inv;
    float sn, c;
    sincosf(ang, &sn, &c);
    o0 = x0 * c - x1 * sn;
    o1 = x1 * c + x0 * sn;
  } else {
    o0 = x0; o1 = x1;
  }
  float am = fmaxf(fabsf(o0), fabsf(o1));
#pragma unroll
  for (int off = 32; off > 0; off >>= 1) am = fmaxf(am, __shfl_xor(am, off));
  const float scale = fmaxf(am / 127.0f, 1e-8f);
  const float q0 = fminf(fmaxf(rintf(o0 / scale), -128.f), 127.f);
  const float q1 = fminf(fmaxf(rintf(o1 / scale), -128.f), 127.f);
  const size_t orow = (size_t)((tok >> 10) * NHEAD + h) * S_LEN + s;
  int8_t* op = o8 + orow * DHEAD;
  op[lane] = (int8_t)(int)q0;
  op[lane + 64] = (int8_t)(int)q1;
  if (lane == 0) oscale[orow] = scale;
}

// -------- V: quant per (b,h,s) row, fold sv in, store TRANSPOSED bf16 [bh][d][s] --------
__global__ __launch_bounds__(256) void vtrans_kernel(
    const float* __restrict__ y, unsigned short* __restrict__ vqT)
{
  __shared__ unsigned short vt[128][80];
  const int tid = threadIdx.x;
  const int wv = tid >> 6, lane = tid & 63;
  const int bh = blockIdx.y, s0 = blockIdx.x * 64;
  const int b = bh >> 5, h = bh & 31;
  for (int it = 0; it < 16; ++it) {
    const int tl = wv * 16 + it;
    const float* yr = y + ((size_t)(b * S_LEN + s0 + tl)) * HDIM + h * DHEAD;
    float x0 = yr[lane], x1 = yr[lane + 64];
    float am = fmaxf(fabsf(x0), fabsf(x1));
#pragma unroll
    for (int off = 32; off > 0; off >>= 1) am = fmaxf(am, __shfl_xor(am, off));
    const float scale = fmaxf(am / 127.0f, 1e-8f);
    const float q0 = fminf(fmaxf(rintf(x0 / scale), -128.f), 127.f);
    const float q1 = fminf(fmaxf(rintf(x1 / scale), -128.f), 127.f);
    vt[lane][tl] = f2bf(q0 * scale);
    vt[lane + 64][tl] = f2bf(q1 * scale);
  }
  __syncthreads();
  const int d = tid >> 1, half = tid & 1;
  unsigned short* op = vqT + ((size_t)bh * 128 + d) * S_LEN + s0 + half * 32;
#pragma unroll
  for (int c = 0; c < 4; ++c)
    *(i32x4*)(op + c * 8) = *(const i32x4*)(&vt[d][half * 32 + c * 8]);
}

// -------- MFMA flash attention, causal-balanced: block does q-tiles (bx, 15-bx) --------
#define QB 64
#define KB 64

__global__ __launch_bounds__(256) void attn_mfma_kernel(
    const int8_t* __restrict__ qq, const float* __restrict__ sq,
    const int8_t* __restrict__ kq, const float* __restrict__ sk,
    const unsigned short* __restrict__ vqT,   // bf16 bits, sv pre-folded
    float* __restrict__ attn)
{
  __shared__ __align__(16) int8_t ks[KB * 128];
  __shared__ __align__(16) unsigned short vs[128 * 64];
  __shared__ __align__(16) unsigned short ps[QB][64];
  __shared__ float sk_t[KB];

  const int tid = threadIdx.x;
  const int w = tid >> 6;
  const int l = tid & 63;
  const int l15 = l & 15;
  const int lg = l >> 4;
  const int lr = l >> 3, g7 = l & 7;
  const int bh = blockIdx.y;
  const size_t bhS = (size_t)bh * S_LEN;
  const int b = bh >> 5, h = bh & 31;
  const int NT = S_LEN / QB;   // 16

  for (int rep = 0; rep < 2; ++rep) {
    const int qt = rep ? (NT - 1 - (int)blockIdx.x) : (int)blockIdx.x;
    const int q0 = qt * QB;
    const int nkt = qt + 1;

    const int qrow = q0 + w * 16 + l15;
    const int8_t* qp = qq + (bhS + qrow) * (size_t)DHEAD;
    const i32x4 qa0 = *(const i32x4*)(qp + lg * 16);
    const i32x4 qa1 = *(const i32x4*)(qp + 64 + lg * 16);

    float sqv[4];
    int qg[4];
#pragma unroll
    for (int r = 0; r < 4; ++r) {
      qg[r] = q0 + w * 16 + lg * 4 + r;
      sqv[r] = sq[bhS + qg[r]] * 0.08838834764831843f * 1.4426950408889634f;
    }

    float rmax[4] = {-3.0e38f, -3.0e38f, -3.0e38f, -3.0e38f};

    // ---------- pass 1: exact row max (log2 domain) ----------
    for (int kt = 0; kt < nkt; ++kt) {
      const int k0 = kt * KB;
#pragma unroll
      for (int i = 0; i < 2; ++i) {
        const int r0 = w * 16 + i * 8;
        gl2lds16(kq + (bhS + k0 + r0 + lr) * (size_t)128 + ((g7 ^ lr) << 4),
                 ks + r0 * 128);
      }
      if (tid < KB) sk_t[tid] = sk[bhS + k0 + tid];
      __syncthreads();
      const bool diag = (kt == nkt - 1);
#pragma unroll
      for (int c = 0; c < 4; ++c) {
        const int krow = c * 16 + l15;
        const i32x4 b0 = *(const i32x4*)(ks + krow * 128 + ((lg ^ (krow & 7)) << 4));
        const i32x4 b1 = *(const i32x4*)(ks + krow * 128 + (((lg + 4) ^ (krow & 7)) << 4));
        i32x4 acc = {0, 0, 0, 0};
        acc = __builtin_amdgcn_mfma_i32_16x16x64_i8(qa0, b0, acc, 0, 0, 0);
        acc = __builtin_amdgcn_mfma_i32_16x16x64_i8(qa1, b1, acc, 0, 0, 0);
        const float skv = sk_t[krow];
        const int kgl = k0 + krow;
#pragma unroll
        for (int r = 0; r < 4; ++r) {
          const float s = (float)acc[r] * sqv[r] * skv;
          if (!diag || (kgl <= qg[r])) rmax[r] = fmaxf(rmax[r], s);
        }
      }
      __syncthreads();
    }
#pragma unroll
    for (int r = 0; r < 4; ++r)
#pragma unroll
      for (int off = 1; off < 16; off <<= 1)
        rmax[r] = fmaxf(rmax[r], __shfl_xor(rmax[r], off));

    // ---------- pass 2: P quant + PV ----------
    float rs[4] = {0.f, 0.f, 0.f, 0.f};
    f32x4 oacc[8];
#pragma unroll
    for (int ds = 0; ds < 8; ++ds) oacc[ds] = (f32x4){0.f, 0.f, 0.f, 0.f};

    const int qloc = w * 16 + l15;
    const int swA0 = (lg ^ (qloc & 7)) << 3;
    const int swA1 = ((lg + 4) ^ (qloc & 7)) << 3;

    for (int kt = 0; kt < nkt; ++kt) {
      const int k0 = kt * KB;
#pragma unroll
      for (int i = 0; i < 2; ++i) {
        const int r0 = w * 16 + i * 8;
        gl2lds16(kq + (bhS + k0 + r0 + lr) * (size_t)128 + ((g7 ^ lr) << 4),
                 ks + r0 * 128);
      }
#pragma unroll
      for (int i = 0; i < 4; ++i) {
        const int r0 = w * 32 + i * 8;
        const unsigned short* src = vqT + ((size_t)bh * 128 + r0 + lr) * S_LEN
                                        + k0 + ((g7 ^ lr) << 3);
        gl2lds16(src, vs + r0 * 64);
      }
      if (tid < KB) sk_t[tid] = sk[bhS + k0 + tid];
      __syncthreads();
      const bool diag = (kt == nkt - 1);

#pragma unroll
      for (int c = 0; c < 4; ++c) {
        const int krow = c * 16 + l15;
        const i32x4 b0 = *(const i32x4*)(ks + krow * 128 + ((lg ^ (krow & 7)) << 4));
        const i32x4 b1 = *(const i32x4*)(ks + krow * 128 + (((lg + 4) ^ (krow & 7)) << 4));
        i32x4 acc = {0, 0, 0, 0};
        acc = __builtin_amdgcn_mfma_i32_16x16x64_i8(qa0, b0, acc, 0, 0, 0);
        acc = __builtin_amdgcn_mfma_i32_16x16x64_i8(qa1, b1, acc, 0, 0, 0);
        const float skv = sk_t[krow];
        const int kgl = k0 + krow;
#pragma unroll
        for (int r = 0; r < 4; ++r) {
          const float s2 = (float)acc[r] * sqv[r] * skv;
          const bool valid = !diag || (kgl <= qg[r]);
          const float e = valid ? exp2f(s2 - rmax[r]) : 0.0f;
          rs[r] += e;
          const float p = rintf(e * 127.0f);
          const int qr = w * 16 + lg * 4 + r;
          const int sidx = (((krow >> 3) ^ (qr & 7)) << 3) | (krow & 7);
          ps[qr][sidx] = f2bf(p);
        }
      }

      const bf16x8 a0 = *(const bf16x8*)&ps[qloc][swA0];
      const bf16x8 a1 = *(const bf16x8*)&ps[qloc][swA1];
#pragma unroll
      for (int ds = 0; ds < 8; ++ds) {
        const int d = ds * 16 + l15;
        const bf16x8 bv0 = *(const bf16x8*)(vs + d * 64 + ((lg ^ (d & 7)) << 3));
        const bf16x8 bv1 = *(const bf16x8*)(vs + d * 64 + (((lg + 4) ^ (d & 7)) << 3));
        oacc[ds] = __builtin_amdgcn_mfma_f32_16x16x32_bf16(a0, bv0, oacc[ds], 0, 0, 0);
        oacc[ds] = __builtin_amdgcn_mfma_f32_16x16x32_bf16(a1, bv1, oacc[ds], 0, 0, 0);
      }
      __syncthreads();
    }

    // ---------- epilogue ----------
#pragma unroll
    for (int r = 0; r < 4; ++r)
#pragma unroll
      for (int off = 1; off < 16; off <<= 1)
        rs[r] += __shfl_xor(rs[r], off);

#pragma unroll
    for (int r = 0; r < 4; ++r) {
      const float inv = 1.0f / (127.0f * rs[r]);
      float* op = attn + ((size_t)(b * S_LEN + qg[r])) * HDIM + h * DHEAD + l15;
#pragma unroll
      for (int ds = 0; ds < 8; ++ds)
        op[ds * 16] = oacc[ds][r] * inv;
    }
  }
}

extern "C" void kernel_launch(void* const* d_in, const int* in_sizes, int n_in,
                              void* d_out, int out_size, void* d_ws, size_t ws_size,
                              hipStream_t stream) {
  const float* hs = (const float*)d_in[0];
  const float* wmat[4] = { (const float*)d_in[1], (const float*)d_in[2],
                           (const float*)d_in[3], (const float*)d_in[4] };

  char* p = (char*)d_ws;
  auto take = [&](size_t sz) { char* r = p; p += (sz + 255) & ~(size_t)255; return r; };

  int8_t* xq8 = (int8_t*)take((size_t)MTOK * HDIM);
  int8_t* w4[4];
  for (int i = 0; i < 4; ++i) w4[i] = (int8_t*)take((size_t)HDIM * HDIM);
  float* sx = (float*)take((size_t)MTOK * 4);
  float* sw[4];
  for (int i = 0; i < 4; ++i) sw[i] = (float*)take((size_t)HDIM * 4);
  float* y = (float*)take((size_t)MTOK * HDIM * 4);
  int8_t* qq8 = (int8_t*)take((size_t)MTOK * HDIM);
  int8_t* kq8 = (int8_t*)take((size_t)MTOK * HDIM);
  unsigned short* vqT = (unsigned short*)take((size_t)MTOK * HDIM * 2);
  float* sqs = (float*)take((size_t)BATCH * NHEAD * S_LEN * 4);
  float* sks = (float*)take((size_t)BATCH * NHEAD * S_LEN * 4);
  float* sattn = (float*)take((size_t)MTOK * 4);

  rowquant_kernel<<<MTOK, 256, 0, stream>>>(hs, xq8, sx, 127.f, -128.f);
  for (int i = 0; i < 4; ++i)
    rowquant_kernel<<<HDIM, 256, 0, stream>>>(wmat[i], w4[i], sw[i], 7.f, -8.f);

  const dim3 gg(HDIM / 128, MTOK / 128);  // (32,16) = 512 blocks
  gemm_i8_dbuf_kernel<<<gg, 256, 0, stream>>>(xq8, sx, w4[0], sw[0], y);
  rope_quant_kernel<<<MTOK * NHEAD / 4, 256, 0, stream>>>(y, qq8, sqs, 1);
  gemm_i8_dbuf_kernel<<<gg, 256, 0, stream>>>(xq8, sx, w4[1], sw[1], y);
  rope_quant_kernel<<<MTOK * NHEAD / 4, 256, 0, stream>>>(y, kq8, sks, 1);
  gemm_i8_dbuf_kernel<<<gg, 256, 0, stream>>>(xq8, sx, w4[2], sw[2], y);
  vtrans_kernel<<<dim3(S_LEN / 64, BATCH * NHEAD), 256, 0, stream>>>(y, vqT);

  attn_mfma_kernel<<<dim3(S_LEN / QB / 2, BATCH * NHEAD), 256, 0, stream>>>(
      qq8, sqs, kq8, sks, vqT, y);

  rowquant_kernel<<<MTOK, 256, 0, stream>>>(y, xq8, sattn, 127.f, -128.f);
  gemm_i8_dbuf_kernel<<<gg, 256, 0, stream>>>(xq8, sattn, w4[3], sw[3], (float*)d_out);
}

// Round 8
// 319.356 us; speedup vs baseline: 1.5326x; 1.2679x over previous
//
#include <hip/hip_runtime.h>
#include <stdint.h>

#define S_LEN 1024
#define HDIM  4096
#define NHEAD 32
#define DHEAD 128
#define BATCH 2
#define MTOK  (BATCH * S_LEN)   // 2048

typedef __attribute__((ext_vector_type(4))) int   i32x4;
typedef __attribute__((ext_vector_type(4))) float f32x4;
typedef __attribute__((ext_vector_type(8))) short bf16x8;

#define GLOBAL_AS __attribute__((address_space(1)))
#define LDS_AS    __attribute__((address_space(3)))

__device__ __forceinline__ void gl2lds16(const void* g, void* l) {
  __builtin_amdgcn_global_load_lds((const GLOBAL_AS unsigned int*)(g),
                                   (LDS_AS unsigned int*)(l), 16, 0, 0);
}

// float -> bf16 bits, round-to-nearest-even (exact for small ints)
__device__ __forceinline__ unsigned short f2bf(float f) {
  unsigned int u = __float_as_uint(f);
  unsigned int r = (u + 0x7fffu + ((u >> 16) & 1u)) >> 16;
  return (unsigned short)r;
}

// -------- per-row symmetric fake-quant: x (row of 4096 f32) -> int8 + scale --------
__global__ __launch_bounds__(256) void rowquant_kernel(
    const float* __restrict__ x, int8_t* __restrict__ q,
    float* __restrict__ scales, float qmax, float clipLo)
{
  const int row = blockIdx.x;
  const int t = threadIdx.x;
  const float* xr = x + (size_t)row * HDIM;
  float4 v[4];
  float am = 0.f;
#pragma unroll
  for (int i = 0; i < 4; ++i) {
    v[i] = ((const float4*)xr)[t + 256 * i];
    am = fmaxf(am, fmaxf(fmaxf(fabsf(v[i].x), fabsf(v[i].y)),
                         fmaxf(fabsf(v[i].z), fabsf(v[i].w))));
  }
#pragma unroll
  for (int off = 32; off > 0; off >>= 1) am = fmaxf(am, __shfl_down(am, off));
  __shared__ float wred[4];
  if ((t & 63) == 0) wred[t >> 6] = am;
  __syncthreads();
  const float m = fmaxf(fmaxf(wred[0], wred[1]), fmaxf(wred[2], wred[3]));
  const float scale = fmaxf(m / qmax, 1e-8f);
  if (t == 0) scales[row] = scale;
  int* qo = (int*)(q + (size_t)row * HDIM);
#pragma unroll
  for (int i = 0; i < 4; ++i) {
    int b0 = (int)fminf(fmaxf(rintf(v[i].x / scale), clipLo), qmax);
    int b1 = (int)fminf(fmaxf(rintf(v[i].y / scale), clipLo), qmax);
    int b2 = (int)fminf(fmaxf(rintf(v[i].z / scale), clipLo), qmax);
    int b3 = (int)fminf(fmaxf(rintf(v[i].w / scale), clipLo), qmax);
    qo[t + 256 * i] = (b0 & 0xff) | ((b1 & 0xff) << 8) | ((b2 & 0xff) << 16) | ((b3 & 0xff) << 24);
  }
}

// -------- RoPE cos/sin tables: [1024][64] each --------
__global__ __launch_bounds__(256) void ropetab_kernel(
    float* __restrict__ ct, float* __restrict__ st)
{
  const int t = blockIdx.x * 256 + threadIdx.x;   // 65536
  const int s = t >> 6, d = t & 63;
  const float inv = powf(10000.0f, -(float)d * (1.0f / 64.0f));
  const float ang = (float)s * inv;
  float sn, c;
  sincosf(ang, &sn, &c);
  ct[t] = c;
  st[t] = sn;
}

// ======== i8 MFMA GEMM, 128x128 tile, 4 waves, 2-phase dbuf, fused epilogue ========
// MODE 0: C write (f32).  MODE 1: rope + per-(token,head) quant8 -> o8/oscale.
// MODE 2: per-(token,head) quant + fold scale + transposed bf16 -> vqT.
template<int MODE>
__global__ __launch_bounds__(256, 2) void gemm_i8_fused_kernel(
    const int8_t* __restrict__ A, const float* __restrict__ sa,
    const int8_t* __restrict__ Bw, const float* __restrict__ sb,
    float* __restrict__ C,
    int8_t* __restrict__ o8, float* __restrict__ oscale,
    const float* __restrict__ ctab, const float* __restrict__ stab,
    unsigned short* __restrict__ vqT)
{
  __shared__ __align__(16) char smem[128 * 129 * 4];   // 66048 B (dbuf 64KB aliased)
  __shared__ float vscale[128];
  int8_t (*asB)[128 * 128] = (int8_t(*)[128 * 128])smem;
  int8_t (*bsB)[128 * 128] = (int8_t(*)[128 * 128])(smem + 32768);
  float (*fx)[129] = (float(*)[129])smem;

  const int flat = blockIdx.y * gridDim.x + blockIdx.x;
  const int nf = (flat & 7) * 64 + (flat >> 3);
  const int bmi = nf & 15, bni = nf >> 4;
  const int bm = bmi * 128, bn = bni * 128;

  const int tid = threadIdx.x;
  const int w = tid >> 6, l = tid & 63;
  const int l15 = l & 15, lg = l >> 4, l7 = l & 7;
  const int lr = l >> 3, g7 = l & 7;
  const int m0 = (w >> 1) * 64, n0 = (w & 1) * 64;

  const int8_t* aT = A + (size_t)(bm + lr) * HDIM + ((g7 ^ lr) << 4);
  const int8_t* bT = Bw + (size_t)(bn + lr) * HDIM + ((g7 ^ lr) << 4);

  i32x4 acc[4][4];
#pragma unroll
  for (int i = 0; i < 4; ++i)
#pragma unroll
    for (int j = 0; j < 4; ++j) acc[i][j] = (i32x4){0, 0, 0, 0};

  auto stage = [&](int t) {
    const int bf = t & 1;
    const size_t k = (size_t)t * 128;
#pragma unroll
    for (int i = 0; i < 4; ++i) {
      const int r0 = w * 32 + i * 8;
      gl2lds16(aT + (size_t)r0 * HDIM + k, asB[bf] + r0 * 128);
      gl2lds16(bT + (size_t)r0 * HDIM + k, bsB[bf] + r0 * 128);
    }
  };

  stage(0);
  asm volatile("s_waitcnt vmcnt(0)" ::: "memory");
  __builtin_amdgcn_s_barrier();

  for (int t = 0; t < 32; ++t) {
    if (t < 31) stage(t + 1);
    const int cur = t & 1;
    __builtin_amdgcn_s_setprio(1);
#pragma unroll
    for (int kk = 0; kk < 2; ++kk) {
      i32x4 aF[4], bF[4];
      const int slot = (((kk << 2) + lg) ^ l7) << 4;
#pragma unroll
      for (int i = 0; i < 4; ++i)
        aF[i] = *(const i32x4*)(asB[cur] + (m0 + i * 16 + l15) * 128 + slot);
#pragma unroll
      for (int j = 0; j < 4; ++j)
        bF[j] = *(const i32x4*)(bsB[cur] + (n0 + j * 16 + l15) * 128 + slot);
#pragma unroll
      for (int i = 0; i < 4; ++i)
#pragma unroll
        for (int j = 0; j < 4; ++j)
          acc[i][j] = __builtin_amdgcn_mfma_i32_16x16x64_i8(aF[i], bF[j], acc[i][j], 0, 0, 0);
    }
    __builtin_amdgcn_s_setprio(0);
    if (t < 31) {
      asm volatile("s_waitcnt vmcnt(0)" ::: "memory");
      __builtin_amdgcn_s_barrier();
    }
  }

  float sbr[4];
#pragma unroll
  for (int j = 0; j < 4; ++j) sbr[j] = sb[bn + n0 + j * 16 + l15];

  if (MODE == 0) {
#pragma unroll
    for (int i = 0; i < 4; ++i) {
#pragma unroll
      for (int r = 0; r < 4; ++r) {
        const int m = bm + m0 + i * 16 + lg * 4 + r;
        const float sm = sa[m];
        float* cp = C + (size_t)m * HDIM + bn + n0 + l15;
#pragma unroll
        for (int j = 0; j < 4; ++j)
          cp[j * 16] = sm * sbr[j] * (float)acc[i][j][r];
      }
    }
    return;
  }

  // ---- scatter scaled f32 tile to LDS ----
  __syncthreads();   // all dbuf reads done before aliasing as fx
#pragma unroll
  for (int i = 0; i < 4; ++i) {
#pragma unroll
    for (int r = 0; r < 4; ++r) {
      const int ml = m0 + i * 16 + lg * 4 + r;
      const float sm = sa[bm + ml];
#pragma unroll
      for (int j = 0; j < 4; ++j)
        fx[ml][n0 + j * 16 + l15] = sm * sbr[j] * (float)acc[i][j][r];
    }
  }
  __syncthreads();

  const int h = bn >> 7;   // one head per block (BN == DHEAD)

  if (MODE == 1) {
    // rope (in-place) + per-(token,head) absmax
    const int row = tid >> 1, half = tid & 1;
    const int sg = bm + row;
    const int b = sg >> 10, s = sg & (S_LEN - 1);
    const float* ct = ctab + (size_t)s * 64;
    const float* st = stab + (size_t)s * 64;
    float am = 0.f;
#pragma unroll
    for (int d0 = 0; d0 < 64; ++d0) {
      const int d = half * 64 + d0;
      const float x0 = fx[row][d];
      const float x1 = fx[row][d ^ 64];
      const float c = ct[d0], sn = st[d0];
      const float v = half ? (x0 * c + x1 * sn) : (x0 * c - x1 * sn);
      fx[row][d] = v;       // lockstep: all lanes read before the write instr
      am = fmaxf(am, fabsf(v));
    }
    am = fmaxf(am, __shfl_xor(am, 1));
    const float scale = fmaxf(am * (1.0f / 127.0f), 1e-8f);
    int8_t* op = o8 + (((size_t)(b * NHEAD + h)) * S_LEN + s) * DHEAD + half * 64;
#pragma unroll
    for (int c4 = 0; c4 < 4; ++c4) {
      i32x4 dw;
#pragma unroll
      for (int u = 0; u < 4; ++u) {
        int pk = 0;
#pragma unroll
        for (int bi = 0; bi < 4; ++bi) {
          const float v = fx[row][half * 64 + c4 * 16 + u * 4 + bi];
          const int q = (int)fminf(fmaxf(rintf(v / scale), -128.f), 127.f);
          pk |= (q & 0xff) << (8 * bi);
        }
        dw[u] = pk;
      }
      *(i32x4*)(op + c4 * 16) = dw;
    }
    if (!half) oscale[((size_t)(b * NHEAD + h)) * S_LEN + s] = scale;
  } else {
    // MODE 2: V quant + fold + transpose to [bh][d][s] bf16
    {
      const int row = tid >> 1, half = tid & 1;
      float am = 0.f;
#pragma unroll
      for (int d0 = 0; d0 < 64; ++d0)
        am = fmaxf(am, fabsf(fx[row][half * 64 + d0]));
      am = fmaxf(am, __shfl_xor(am, 1));
      if (!half) vscale[row] = fmaxf(am * (1.0f / 127.0f), 1e-8f);
    }
    __syncthreads();
    {
      const int d = tid >> 1, sh = tid & 1;
      const int b = bm >> 10;
      const int bh = b * NHEAD + h;
      unsigned short* op = vqT + ((size_t)bh * DHEAD + d) * S_LEN + (bm & (S_LEN - 1)) + sh * 64;
#pragma unroll
      for (int c8 = 0; c8 < 8; ++c8) {
        i32x4 dw;
#pragma unroll
        for (int u = 0; u < 4; ++u) {
          const int sl = sh * 64 + c8 * 8 + u * 2;
          const float sc0 = vscale[sl], sc1 = vscale[sl + 1];
          const float q0 = fminf(fmaxf(rintf(fx[sl][d] / sc0), -128.f), 127.f);
          const float q1 = fminf(fmaxf(rintf(fx[sl + 1][d] / sc1), -128.f), 127.f);
          dw[u] = (int)f2bf(q0 * sc0) | ((int)f2bf(q1 * sc1) << 16);
        }
        *(i32x4*)(op + c8 * 8) = dw;
      }
    }
  }
}

// -------- MFMA flash attention, causal-balanced + XCD-affinity grid --------
#define QB 64
#define KB 64

__global__ __launch_bounds__(256) void attn_mfma_kernel(
    const int8_t* __restrict__ qq, const float* __restrict__ sq,
    const int8_t* __restrict__ kq, const float* __restrict__ sk,
    const unsigned short* __restrict__ vqT,   // bf16 bits, sv pre-folded
    float* __restrict__ attn)
{
  __shared__ __align__(16) int8_t ks[KB * 128];
  __shared__ __align__(16) unsigned short vs[128 * 64];
  __shared__ __align__(16) unsigned short ps[QB][64];
  __shared__ float sk_t[KB];

  const int tid = threadIdx.x;
  const int w = tid >> 6;
  const int l = tid & 63;
  const int l15 = l & 15;
  const int lg = l >> 4;
  const int lr = l >> 3, g7 = l & 7;
  // XCD-affinity decode: all 8 q-blocks of a bh share XCD (= bflat % 8)
  const int bflat = blockIdx.x;
  const int bh = (bflat & 7) + 8 * (bflat >> 6);
  const int qxb = (bflat >> 3) & 7;
  const size_t bhS = (size_t)bh * S_LEN;
  const int b = bh >> 5, h = bh & 31;
  const int NT = S_LEN / QB;   // 16

  for (int rep = 0; rep < 2; ++rep) {
    const int qt = rep ? (NT - 1 - qxb) : qxb;
    const int q0 = qt * QB;
    const int nkt = qt + 1;

    const int qrow = q0 + w * 16 + l15;
    const int8_t* qp = qq + (bhS + qrow) * (size_t)DHEAD;
    const i32x4 qa0 = *(const i32x4*)(qp + lg * 16);
    const i32x4 qa1 = *(const i32x4*)(qp + 64 + lg * 16);

    float sqv[4];
    int qg[4];
#pragma unroll
    for (int r = 0; r < 4; ++r) {
      qg[r] = q0 + w * 16 + lg * 4 + r;
      sqv[r] = sq[bhS + qg[r]] * 0.08838834764831843f * 1.4426950408889634f;
    }

    float rmax[4] = {-3.0e38f, -3.0e38f, -3.0e38f, -3.0e38f};

    // ---------- pass 1: exact row max (log2 domain) ----------
    for (int kt = 0; kt < nkt; ++kt) {
      const int k0 = kt * KB;
#pragma unroll
      for (int i = 0; i < 2; ++i) {
        const int r0 = w * 16 + i * 8;
        gl2lds16(kq + (bhS + k0 + r0 + lr) * (size_t)128 + ((g7 ^ lr) << 4),
                 ks + r0 * 128);
      }
      if (tid < KB) sk_t[tid] = sk[bhS + k0 + tid];
      __syncthreads();
      const bool diag = (kt == nkt - 1);
#pragma unroll
      for (int c = 0; c < 4; ++c) {
        const int krow = c * 16 + l15;
        const i32x4 b0 = *(const i32x4*)(ks + krow * 128 + ((lg ^ (krow & 7)) << 4));
        const i32x4 b1 = *(const i32x4*)(ks + krow * 128 + (((lg + 4) ^ (krow & 7)) << 4));
        i32x4 acc = {0, 0, 0, 0};
        acc = __builtin_amdgcn_mfma_i32_16x16x64_i8(qa0, b0, acc, 0, 0, 0);
        acc = __builtin_amdgcn_mfma_i32_16x16x64_i8(qa1, b1, acc, 0, 0, 0);
        const float skv = sk_t[krow];
        const int kgl = k0 + krow;
#pragma unroll
        for (int r = 0; r < 4; ++r) {
          const float s = (float)acc[r] * sqv[r] * skv;
          if (!diag || (kgl <= qg[r])) rmax[r] = fmaxf(rmax[r], s);
        }
      }
      __syncthreads();
    }
#pragma unroll
    for (int r = 0; r < 4; ++r)
#pragma unroll
      for (int off = 1; off < 16; off <<= 1)
        rmax[r] = fmaxf(rmax[r], __shfl_xor(rmax[r], off));

    // ---------- pass 2: P quant + PV ----------
    float rs[4] = {0.f, 0.f, 0.f, 0.f};
    f32x4 oacc[8];
#pragma unroll
    for (int ds = 0; ds < 8; ++ds) oacc[ds] = (f32x4){0.f, 0.f, 0.f, 0.f};

    const int qloc = w * 16 + l15;
    const int swA0 = (lg ^ (qloc & 7)) << 3;
    const int swA1 = ((lg + 4) ^ (qloc & 7)) << 3;

    for (int kt = 0; kt < nkt; ++kt) {
      const int k0 = kt * KB;
#pragma unroll
      for (int i = 0; i < 2; ++i) {
        const int r0 = w * 16 + i * 8;
        gl2lds16(kq + (bhS + k0 + r0 + lr) * (size_t)128 + ((g7 ^ lr) << 4),
                 ks + r0 * 128);
      }
#pragma unroll
      for (int i = 0; i < 4; ++i) {
        const int r0 = w * 32 + i * 8;
        const unsigned short* src = vqT + ((size_t)bh * 128 + r0 + lr) * S_LEN
                                        + k0 + ((g7 ^ lr) << 3);
        gl2lds16(src, vs + r0 * 64);
      }
      if (tid < KB) sk_t[tid] = sk[bhS + k0 + tid];
      __syncthreads();
      const bool diag = (kt == nkt - 1);

#pragma unroll
      for (int c = 0; c < 4; ++c) {
        const int krow = c * 16 + l15;
        const i32x4 b0 = *(const i32x4*)(ks + krow * 128 + ((lg ^ (krow & 7)) << 4));
        const i32x4 b1 = *(const i32x4*)(ks + krow * 128 + (((lg + 4) ^ (krow & 7)) << 4));
        i32x4 acc = {0, 0, 0, 0};
        acc = __builtin_amdgcn_mfma_i32_16x16x64_i8(qa0, b0, acc, 0, 0, 0);
        acc = __builtin_amdgcn_mfma_i32_16x16x64_i8(qa1, b1, acc, 0, 0, 0);
        const float skv = sk_t[krow];
        const int kgl = k0 + krow;
#pragma unroll
        for (int r = 0; r < 4; ++r) {
          const float s2 = (float)acc[r] * sqv[r] * skv;
          const bool valid = !diag || (kgl <= qg[r]);
          const float e = valid ? exp2f(s2 - rmax[r]) : 0.0f;
          rs[r] += e;
          const float p = rintf(e * 127.0f);
          const int qr = w * 16 + lg * 4 + r;
          const int sidx = (((krow >> 3) ^ (qr & 7)) << 3) | (krow & 7);
          ps[qr][sidx] = f2bf(p);
        }
      }

      const bf16x8 a0 = *(const bf16x8*)&ps[qloc][swA0];
      const bf16x8 a1 = *(const bf16x8*)&ps[qloc][swA1];
#pragma unroll
      for (int ds = 0; ds < 8; ++ds) {
        const int d = ds * 16 + l15;
        const bf16x8 bv0 = *(const bf16x8*)(vs + d * 64 + ((lg ^ (d & 7)) << 3));
        const bf16x8 bv1 = *(const bf16x8*)(vs + d * 64 + (((lg + 4) ^ (d & 7)) << 3));
        oacc[ds] = __builtin_amdgcn_mfma_f32_16x16x32_bf16(a0, bv0, oacc[ds], 0, 0, 0);
        oacc[ds] = __builtin_amdgcn_mfma_f32_16x16x32_bf16(a1, bv1, oacc[ds], 0, 0, 0);
      }
      __syncthreads();
    }

    // ---------- epilogue ----------
#pragma unroll
    for (int r = 0; r < 4; ++r)
#pragma unroll
      for (int off = 1; off < 16; off <<= 1)
        rs[r] += __shfl_xor(rs[r], off);

#pragma unroll
    for (int r = 0; r < 4; ++r) {
      const float inv = 1.0f / (127.0f * rs[r]);
      float* op = attn + ((size_t)(b * S_LEN + qg[r])) * HDIM + h * DHEAD + l15;
#pragma unroll
      for (int ds = 0; ds < 8; ++ds)
        op[ds * 16] = oacc[ds][r] * inv;
    }
  }
}

extern "C" void kernel_launch(void* const* d_in, const int* in_sizes, int n_in,
                              void* d_out, int out_size, void* d_ws, size_t ws_size,
                              hipStream_t stream) {
  const float* hs = (const float*)d_in[0];
  const float* wmat[4] = { (const float*)d_in[1], (const float*)d_in[2],
                           (const float*)d_in[3], (const float*)d_in[4] };

  char* p = (char*)d_ws;
  auto take = [&](size_t sz) { char* r = p; p += (sz + 255) & ~(size_t)255; return r; };

  int8_t* xq8 = (int8_t*)take((size_t)MTOK * HDIM);
  int8_t* w4[4];
  for (int i = 0; i < 4; ++i) w4[i] = (int8_t*)take((size_t)HDIM * HDIM);
  float* sx = (float*)take((size_t)MTOK * 4);
  float* sw[4];
  for (int i = 0; i < 4; ++i) sw[i] = (float*)take((size_t)HDIM * 4);
  float* y = (float*)take((size_t)MTOK * HDIM * 4);
  int8_t* qq8 = (int8_t*)take((size_t)MTOK * HDIM);
  int8_t* kq8 = (int8_t*)take((size_t)MTOK * HDIM);
  unsigned short* vqT = (unsigned short*)take((size_t)MTOK * HDIM * 2);
  float* sqs = (float*)take((size_t)BATCH * NHEAD * S_LEN * 4);
  float* sks = (float*)take((size_t)BATCH * NHEAD * S_LEN * 4);
  float* sattn = (float*)take((size_t)MTOK * 4);
  float* ctab = (float*)take((size_t)S_LEN * 64 * 4);
  float* stab = (float*)take((size_t)S_LEN * 64 * 4);

  rowquant_kernel<<<MTOK, 256, 0, stream>>>(hs, xq8, sx, 127.f, -128.f);
  for (int i = 0; i < 4; ++i)
    rowquant_kernel<<<HDIM, 256, 0, stream>>>(wmat[i], w4[i], sw[i], 7.f, -8.f);
  ropetab_kernel<<<S_LEN * 64 / 256, 256, 0, stream>>>(ctab, stab);

  const dim3 gg(HDIM / 128, MTOK / 128);  // (32,16) = 512 blocks
  // Q: fused rope+quant
  gemm_i8_fused_kernel<1><<<gg, 256, 0, stream>>>(
      xq8, sx, w4[0], sw[0], nullptr, qq8, sqs, ctab, stab, nullptr);
  // K: fused rope+quant
  gemm_i8_fused_kernel<1><<<gg, 256, 0, stream>>>(
      xq8, sx, w4[1], sw[1], nullptr, kq8, sks, ctab, stab, nullptr);
  // V: fused quant + transpose
  gemm_i8_fused_kernel<2><<<gg, 256, 0, stream>>>(
      xq8, sx, w4[2], sw[2], nullptr, nullptr, nullptr, nullptr, nullptr, vqT);

  attn_mfma_kernel<<<512, 256, 0, stream>>>(qq8, sqs, kq8, sks, vqT, y);

  rowquant_kernel<<<MTOK, 256, 0, stream>>>(y, xq8, sattn, 127.f, -128.f);
  gemm_i8_fused_kernel<0><<<gg, 256, 0, stream>>>(
      xq8, sattn, w4[3], sw[3], (float*)d_out, nullptr, nullptr, nullptr, nullptr, nullptr);
}